// Round 1
// baseline (1722.190 us; speedup 1.0000x reference)
//
#include <hip/hip_runtime.h>

#define B_SZ  4096
#define NB    64
#define DIM   512
#define INTER 128
#define EPSV  1e-5f

using f32x4  = __attribute__((ext_vector_type(4))) float;
using bf16x8 = __attribute__((ext_vector_type(8))) __bf16;
using short8 = __attribute__((ext_vector_type(8))) short;

static __device__ __forceinline__ unsigned short f2bf(float f) {
    union { float f; unsigned u; } v; v.f = f;
    return (unsigned short)((v.u + 0x7fffu + ((v.u >> 16) & 1u)) >> 16);
}

static __device__ __forceinline__ f32x4 mfma16(short8 a, short8 b, f32x4 c) {
    return __builtin_amdgcn_mfma_f32_16x16x32_bf16(
        __builtin_bit_cast(bf16x8, a), __builtin_bit_cast(bf16x8, b), c, 0, 0, 0);
}

// ---- prep: W1,W2 -> bf16 ; fold BN constants into scale/bias -------------
__global__ void prep_kernel(
    const float4* __restrict__ W1, const float4* __restrict__ W2,
    const float* __restrict__ b1, const float* __restrict__ g1,
    const float* __restrict__ beta1, const float* __restrict__ m1,
    const float* __restrict__ v1,
    const float* __restrict__ b2, const float* __restrict__ g2,
    const float* __restrict__ beta2, const float* __restrict__ m2,
    const float* __restrict__ v2,
    ushort4* __restrict__ w1bf, ushort4* __restrict__ w2bf,
    float* __restrict__ sc1, float* __restrict__ bi1,
    float* __restrict__ sc2, float* __restrict__ bi2)
{
    int idx = blockIdx.x * blockDim.x + threadIdx.x;  // 0 .. 1048575
    float4 a = W1[idx];
    ushort4 pa; pa.x = f2bf(a.x); pa.y = f2bf(a.y); pa.z = f2bf(a.z); pa.w = f2bf(a.w);
    w1bf[idx] = pa;
    float4 b = W2[idx];
    ushort4 pb; pb.x = f2bf(b.x); pb.y = f2bf(b.y); pb.z = f2bf(b.z); pb.w = f2bf(b.w);
    w2bf[idx] = pb;
    if (idx < NB * INTER) {
        float s = g1[idx] * rsqrtf(v1[idx] + EPSV);
        sc1[idx] = s;
        bi1[idx] = (b1[idx] - m1[idx]) * s + beta1[idx];
    }
    if (idx < NB * DIM) {
        float s = g2[idx] * rsqrtf(v2[idx] + EPSV);
        sc2[idx] = s;
        bi2[idx] = (b2[idx] - m2[idx]) * s + beta2[idx];
    }
}

// ---- sum over branches: s[b,d] = sum_n t[b,n,d], stored bf16 -------------
__global__ void sum_kernel(const float* __restrict__ t, unsigned short* __restrict__ sbf)
{
    int tid = threadIdx.x;
    int b = blockIdx.x * 2 + (tid >> 7);
    int c = tid & 127;                       // float4 column index (0..127)
    const float4* tb = (const float4*)t + (size_t)b * (NB * DIM / 4) + c;
    float4 acc = tb[0];
    for (int n = 1; n < NB; ++n) {
        float4 v = tb[n * (DIM / 4)];
        acc.x += v.x; acc.y += v.y; acc.z += v.z; acc.w += v.w;
    }
    ushort4 o; o.x = f2bf(acc.x); o.y = f2bf(acc.y); o.z = f2bf(acc.z); o.w = f2bf(acc.w);
    ((ushort4*)sbf)[(size_t)b * 128 + c] = o;
}

__global__ void zero_kernel(float4* __restrict__ out)
{
    out[blockIdx.x * 256 + threadIdx.x] = (float4){0.f, 0.f, 0.f, 0.f};
}

// ---- fused grouped GEMM1 -> BN/ReLU -> GEMM2 -> BN/sigmoid -> gate -------
// grid = 512: n_tile = blk & 7 (XCD-resident weight slice), b_tile = blk >> 3
// block = 512 (8 waves): wave w -> m-tile (w&3), half (w>>2)
__global__ __launch_bounds__(512, 2) void fused_kernel(
    const float* __restrict__ t,
    const unsigned short* __restrict__ w1bf,
    const unsigned short* __restrict__ w2bf,
    const unsigned short* __restrict__ sbf,
    const float* __restrict__ sc1, const float* __restrict__ bi1,
    const float* __restrict__ sc2, const float* __restrict__ bi2,
    float* __restrict__ out)
{
    __shared__ unsigned short sH[64 * 136];   // h tile, padded stride 136

    const int blk    = blockIdx.x;
    const int n_tile = blk & 7;
    const int b0     = (blk >> 3) * 64;

    const int tid  = threadIdx.x;
    const int w    = tid >> 6;
    const int lane = tid & 63;
    const int quad = lane >> 4;
    const int l16  = lane & 15;
    const int mt   = w & 3;      // m-tile (16 rows)
    const int half = w >> 2;     // splits N-dim of both GEMMs

    // A-stripe of s: rows (b0 + mt*16 + l16), full K=512, kept in registers,
    // reused by all 8 branches.
    short8 aS[16];
    {
        const unsigned short* sp = sbf + ((size_t)(b0 + mt * 16 + l16) << 9) + (quad << 3);
        #pragma unroll
        for (int s = 0; s < 16; ++s)
            aS[s] = *(const short8*)(sp + s * 32);
    }

    f32x4 opart[16];
    #pragma unroll
    for (int c = 0; c < 16; ++c) opart[c] = (f32x4){0.f, 0.f, 0.f, 0.f};

    for (int j = 0; j < 8; ++j) {
        const int n = n_tile * 8 + j;

        // ---- GEMM1: h[64x128] = s_tile @ W1[n]^T  (M=64,N=128,K=512) ----
        f32x4 acc1[4];
        #pragma unroll
        for (int c = 0; c < 4; ++c) acc1[c] = (f32x4){0.f, 0.f, 0.f, 0.f};
        const unsigned short* w1n = w1bf + (size_t)n * INTER * DIM;
        #pragma unroll
        for (int s = 0; s < 16; ++s) {
            #pragma unroll
            for (int c = 0; c < 4; ++c) {
                const int it = half * 4 + c;
                short8 bfrag = *(const short8*)(w1n + ((size_t)(it * 16 + l16) << 9) + s * 32 + (quad << 3));
                acc1[c] = mfma16(aS[s], bfrag, acc1[c]);
            }
        }
        // BN1 + ReLU -> sH (bf16)
        #pragma unroll
        for (int c = 0; c < 4; ++c) {
            const int i = (half * 4 + c) * 16 + l16;
            const float sc = sc1[n * INTER + i];
            const float bi = bi1[n * INTER + i];
            #pragma unroll
            for (int r = 0; r < 4; ++r) {
                const int m = mt * 16 + quad * 4 + r;
                float h = acc1[c][r] * sc + bi;
                h = h > 0.f ? h : 0.f;
                sH[m * 136 + i] = f2bf(h);
            }
        }
        __syncthreads();

        // ---- GEMM2: y[64x512] = h @ W2[n]^T (M=64,N=512,K=128) + gate ----
        const unsigned short* w2n = w2bf + (size_t)n * DIM * INTER;
        #pragma unroll
        for (int ch = 0; ch < 2; ++ch) {
            f32x4 acc2[8];
            #pragma unroll
            for (int c = 0; c < 8; ++c) acc2[c] = (f32x4){0.f, 0.f, 0.f, 0.f};
            #pragma unroll
            for (int s = 0; s < 4; ++s) {
                short8 a = *(const short8*)(&sH[(mt * 16 + l16) * 136 + s * 32 + (quad << 3)]);
                #pragma unroll
                for (int c = 0; c < 8; ++c) {
                    const int dt = half * 16 + ch * 8 + c;
                    short8 bfrag = *(const short8*)(w2n + ((size_t)(dt * 16 + l16) << 7) + s * 32 + (quad << 3));
                    acc2[c] = mfma16(a, bfrag, acc2[c]);
                }
            }
            // BN2 + sigmoid + gate with t
            #pragma unroll
            for (int c = 0; c < 8; ++c) {
                const int d = (half * 16 + ch * 8 + c) * 16 + l16;
                const float sc = sc2[n * DIM + d];
                const float bi = bi2[n * DIM + d];
                #pragma unroll
                for (int r = 0; r < 4; ++r) {
                    const int m = mt * 16 + quad * 4 + r;
                    float y  = acc2[c][r] * sc + bi;
                    float wv = 1.f / (1.f + __expf(-y));
                    float tv = t[((size_t)(b0 + m) * NB + n) * DIM + d];
                    opart[ch * 8 + c][r] += wv * tv;
                }
            }
        }
        __syncthreads();
    }

    // accumulate partial (this block's 8 branches) into out
    #pragma unroll
    for (int c = 0; c < 16; ++c) {
        const int d = (half * 16 + c) * 16 + l16;
        #pragma unroll
        for (int r = 0; r < 4; ++r) {
            const int m = mt * 16 + quad * 4 + r;
            unsafeAtomicAdd(&out[(size_t)(b0 + m) * DIM + d], opart[c][r] * 3.0f);
        }
    }
}

extern "C" void kernel_launch(void* const* d_in, const int* in_sizes, int n_in,
                              void* d_out, int out_size, void* d_ws, size_t ws_size,
                              hipStream_t stream)
{
    const float* t     = (const float*)d_in[0];
    const float* W1    = (const float*)d_in[1];
    const float* b1    = (const float*)d_in[2];
    const float* g1    = (const float*)d_in[3];
    const float* beta1 = (const float*)d_in[4];
    const float* m1    = (const float*)d_in[5];
    const float* v1    = (const float*)d_in[6];
    const float* W2    = (const float*)d_in[7];
    const float* b2    = (const float*)d_in[8];
    const float* g2    = (const float*)d_in[9];
    const float* beta2 = (const float*)d_in[10];
    const float* m2    = (const float*)d_in[11];
    const float* v2    = (const float*)d_in[12];

    char* ws = (char*)d_ws;
    unsigned short* w1bf = (unsigned short*)(ws);                 //  8,388,608 B
    unsigned short* w2bf = (unsigned short*)(ws + 8388608);       //  8,388,608 B
    unsigned short* sbf  = (unsigned short*)(ws + 16777216);      //  4,194,304 B
    float* sc1 = (float*)(ws + 20971520);                         //     32,768 B
    float* bi1 = (float*)(ws + 21004288);                         //     32,768 B
    float* sc2 = (float*)(ws + 21037056);                         //    131,072 B
    float* bi2 = (float*)(ws + 21168128);                         //    131,072 B

    prep_kernel<<<4096, 256, 0, stream>>>(
        (const float4*)W1, (const float4*)W2,
        b1, g1, beta1, m1, v1, b2, g2, beta2, m2, v2,
        (ushort4*)w1bf, (ushort4*)w2bf, sc1, bi1, sc2, bi2);

    sum_kernel<<<2048, 256, 0, stream>>>(t, sbf);

    zero_kernel<<<2048, 256, 0, stream>>>((float4*)d_out);

    fused_kernel<<<512, 512, 0, stream>>>(
        t, w1bf, w2bf, sbf, sc1, bi1, sc2, bi2, (float*)d_out);
}

// Round 2
// 1205.128 us; speedup vs baseline: 1.4291x; 1.4291x over previous
//
#include <hip/hip_runtime.h>

#define B_SZ  4096
#define NB    64
#define DIM   512
#define INTER 128
#define EPSV  1e-5f

using f32x4  = __attribute__((ext_vector_type(4))) float;
using bf16x8 = __attribute__((ext_vector_type(8))) __bf16;
using short8 = __attribute__((ext_vector_type(8))) short;

static __device__ __forceinline__ unsigned short f2bf(float f) {
    union { float f; unsigned u; } v; v.f = f;
    return (unsigned short)((v.u + 0x7fffu + ((v.u >> 16) & 1u)) >> 16);
}

static __device__ __forceinline__ f32x4 mfma16(short8 a, short8 b, f32x4 c) {
    return __builtin_amdgcn_mfma_f32_16x16x32_bf16(
        __builtin_bit_cast(bf16x8, a), __builtin_bit_cast(bf16x8, b), c, 0, 0, 0);
}

// ---- prep: W1,W2 -> bf16 ; fold BN constants into scale/bias -------------
__global__ void prep_kernel(
    const float4* __restrict__ W1, const float4* __restrict__ W2,
    const float* __restrict__ b1, const float* __restrict__ g1,
    const float* __restrict__ beta1, const float* __restrict__ m1,
    const float* __restrict__ v1,
    const float* __restrict__ b2, const float* __restrict__ g2,
    const float* __restrict__ beta2, const float* __restrict__ m2,
    const float* __restrict__ v2,
    ushort4* __restrict__ w1bf, ushort4* __restrict__ w2bf,
    float* __restrict__ sc1, float* __restrict__ bi1,
    float* __restrict__ sc2, float* __restrict__ bi2)
{
    int idx = blockIdx.x * blockDim.x + threadIdx.x;  // 0 .. 1048575
    float4 a = W1[idx];
    ushort4 pa; pa.x = f2bf(a.x); pa.y = f2bf(a.y); pa.z = f2bf(a.z); pa.w = f2bf(a.w);
    w1bf[idx] = pa;
    float4 b = W2[idx];
    ushort4 pb; pb.x = f2bf(b.x); pb.y = f2bf(b.y); pb.z = f2bf(b.z); pb.w = f2bf(b.w);
    w2bf[idx] = pb;
    if (idx < NB * INTER) {
        float s = g1[idx] * rsqrtf(v1[idx] + EPSV);
        sc1[idx] = s;
        bi1[idx] = (b1[idx] - m1[idx]) * s + beta1[idx];
    }
    if (idx < NB * DIM) {
        float s = g2[idx] * rsqrtf(v2[idx] + EPSV);
        sc2[idx] = s;
        bi2[idx] = (b2[idx] - m2[idx]) * s + beta2[idx];
    }
}

// ---- sum over branches: s[b,d] = sum_n t[b,n,d], stored bf16 -------------
__global__ void sum_kernel(const float* __restrict__ t, unsigned short* __restrict__ sbf)
{
    int tid = threadIdx.x;
    int b = blockIdx.x * 2 + (tid >> 7);
    int c = tid & 127;                       // float4 column index (0..127)
    const float4* tb = (const float4*)t + (size_t)b * (NB * DIM / 4) + c;
    float4 acc = tb[0];
    for (int n = 1; n < NB; ++n) {
        float4 v = tb[n * (DIM / 4)];
        acc.x += v.x; acc.y += v.y; acc.z += v.z; acc.w += v.w;
    }
    ushort4 o; o.x = f2bf(acc.x); o.y = f2bf(acc.y); o.z = f2bf(acc.z); o.w = f2bf(acc.w);
    ((ushort4*)sbf)[(size_t)b * 128 + c] = o;
}

__global__ void zero_kernel(float4* __restrict__ out)
{
    out[blockIdx.x * 256 + threadIdx.x] = (float4){0.f, 0.f, 0.f, 0.f};
}

// ---- phase A: h[n][b][i] = relu(BN1(s @ W1[n]^T)), bf16, n-major ---------
// grid (32 btiles, 64 n), 256 threads = 4 waves.
// Block tile: M=128 (b rows), N=128 (all inter), K=512.
// Wave w: m-half = w&1 (64 rows), i-half = w>>1 (64 cols).
// No LDS, no barriers: A/B fragments streamed straight from L2.
__global__ __launch_bounds__(256) void gemm1_kernel(
    const unsigned short* __restrict__ sbf,
    const unsigned short* __restrict__ w1bf,
    const float* __restrict__ sc1, const float* __restrict__ bi1,
    unsigned short* __restrict__ h)
{
    const int btile = blockIdx.x;       // 0..31
    const int n     = blockIdx.y;       // 0..63
    const int tid  = threadIdx.x;
    const int w    = tid >> 6;
    const int lane = tid & 63;
    const int quad = lane >> 4;
    const int l16  = lane & 15;
    const int m0 = btile * 128 + (w & 1) * 64;
    const int i0 = (w >> 1) * 64;

    f32x4 acc[4][4];
    #pragma unroll
    for (int a = 0; a < 4; ++a)
        #pragma unroll
        for (int c = 0; c < 4; ++c) acc[a][c] = (f32x4){0.f, 0.f, 0.f, 0.f};

    const unsigned short* w1n = w1bf + (size_t)n * (INTER * DIM);
    const unsigned short* abase = sbf + (size_t)(m0 + l16) * DIM + (quad << 3);
    const unsigned short* bbase = w1n + (size_t)(i0 + l16) * DIM + (quad << 3);

    #pragma unroll 2
    for (int s = 0; s < 16; ++s) {
        short8 af[4], bf[4];
        #pragma unroll
        for (int a = 0; a < 4; ++a)
            af[a] = *(const short8*)(abase + (size_t)(a * 16) * DIM + s * 32);
        #pragma unroll
        for (int c = 0; c < 4; ++c)
            bf[c] = *(const short8*)(bbase + (size_t)(c * 16) * DIM + s * 32);
        #pragma unroll
        for (int a = 0; a < 4; ++a)
            #pragma unroll
            for (int c = 0; c < 4; ++c)
                acc[a][c] = mfma16(af[a], bf[c], acc[a][c]);
    }

    // epilogue: BN1 + ReLU -> h[n][b][i] (bf16)
    unsigned short* hn = h + (size_t)n * (B_SZ * INTER);
    #pragma unroll
    for (int c = 0; c < 4; ++c) {
        const int i = i0 + c * 16 + l16;
        const float sc = sc1[n * INTER + i];
        const float bi = bi1[n * INTER + i];
        #pragma unroll
        for (int a = 0; a < 4; ++a) {
            #pragma unroll
            for (int r = 0; r < 4; ++r) {
                const int m = m0 + a * 16 + quad * 4 + r;
                float v = acc[a][c][r] * sc + bi;
                v = v > 0.f ? v : 0.f;
                hn[(size_t)m * INTER + i] = f2bf(v);
            }
        }
    }
}

// ---- phase B: out[b,d] += sum_n sigmoid(BN2(h_n @ W2[n]^T)) * t * 3 ------
// grid (64 btiles, 8 dtiles, 2 ngroups), 256 threads = 4 waves.
// Block tile: 64 b-rows x 64 d; wave w owns rows w*16..+15 (full 64 d).
// Loops 32 branches, out-acc in registers; t read exactly once (HBM stream).
__global__ __launch_bounds__(256) void gemm2_kernel(
    const float* __restrict__ t,
    const unsigned short* __restrict__ h,
    const unsigned short* __restrict__ w2bf,
    const float* __restrict__ sc2, const float* __restrict__ bi2,
    float* __restrict__ out)
{
    const int btile = blockIdx.x;   // 0..63
    const int dtile = blockIdx.y;   // 0..7
    const int ng    = blockIdx.z;   // 0..1
    const int tid  = threadIdx.x;
    const int w    = tid >> 6;
    const int lane = tid & 63;
    const int quad = lane >> 4;
    const int l16  = lane & 15;
    const int d0 = dtile * 64;

    f32x4 oacc[4];
    #pragma unroll
    for (int c = 0; c < 4; ++c) oacc[c] = (f32x4){0.f, 0.f, 0.f, 0.f};

    const unsigned short* habase =
        h + (size_t)(btile * 64 + w * 16 + l16) * INTER + (quad << 3);

    for (int n = ng * 32; n < ng * 32 + 32; ++n) {
        const unsigned short* hn  = habase + (size_t)n * (B_SZ * INTER);
        const unsigned short* w2n = w2bf + (size_t)n * (DIM * INTER)
                                  + (size_t)(d0 + l16) * INTER + (quad << 3);
        f32x4 yacc[4];
        #pragma unroll
        for (int c = 0; c < 4; ++c) yacc[c] = (f32x4){0.f, 0.f, 0.f, 0.f};

        #pragma unroll
        for (int s = 0; s < 4; ++s) {
            short8 af = *(const short8*)(hn + s * 32);
            #pragma unroll
            for (int c = 0; c < 4; ++c) {
                short8 bf = *(const short8*)(w2n + (size_t)(c * 16) * INTER + s * 32);
                yacc[c] = mfma16(af, bf, yacc[c]);
            }
        }

        // BN2 + sigmoid + gate with t
        #pragma unroll
        for (int c = 0; c < 4; ++c) {
            const int d = d0 + c * 16 + l16;
            const float sc = sc2[n * DIM + d];
            const float bi = bi2[n * DIM + d];
            #pragma unroll
            for (int r = 0; r < 4; ++r) {
                const int m = btile * 64 + w * 16 + quad * 4 + r;
                float y  = yacc[c][r] * sc + bi;
                float wv = 1.f / (1.f + __expf(-y));
                float tv = t[((size_t)m * NB + n) * DIM + d];
                oacc[c][r] += wv * tv;
            }
        }
    }

    #pragma unroll
    for (int c = 0; c < 4; ++c) {
        const int d = d0 + c * 16 + l16;
        #pragma unroll
        for (int r = 0; r < 4; ++r) {
            const int m = btile * 64 + w * 16 + quad * 4 + r;
            unsafeAtomicAdd(&out[(size_t)m * DIM + d], oacc[c][r] * 3.0f);
        }
    }
}

extern "C" void kernel_launch(void* const* d_in, const int* in_sizes, int n_in,
                              void* d_out, int out_size, void* d_ws, size_t ws_size,
                              hipStream_t stream)
{
    const float* t     = (const float*)d_in[0];
    const float* W1    = (const float*)d_in[1];
    const float* b1    = (const float*)d_in[2];
    const float* g1    = (const float*)d_in[3];
    const float* beta1 = (const float*)d_in[4];
    const float* m1    = (const float*)d_in[5];
    const float* v1    = (const float*)d_in[6];
    const float* W2    = (const float*)d_in[7];
    const float* b2    = (const float*)d_in[8];
    const float* g2    = (const float*)d_in[9];
    const float* beta2 = (const float*)d_in[10];
    const float* m2    = (const float*)d_in[11];
    const float* v2    = (const float*)d_in[12];

    char* ws = (char*)d_ws;
    unsigned short* w1bf = (unsigned short*)(ws);                 //  8,388,608 B
    unsigned short* w2bf = (unsigned short*)(ws + 8388608);       //  8,388,608 B
    unsigned short* sbf  = (unsigned short*)(ws + 16777216);      //  4,194,304 B
    float* sc1 = (float*)(ws + 20971520);                         //     32,768 B
    float* bi1 = (float*)(ws + 21004288);                         //     32,768 B
    float* sc2 = (float*)(ws + 21037056);                         //    131,072 B
    float* bi2 = (float*)(ws + 21168128);                         //    131,072 B
    unsigned short* hbuf = (unsigned short*)(ws + 21299200);      // 67,108,864 B

    prep_kernel<<<4096, 256, 0, stream>>>(
        (const float4*)W1, (const float4*)W2,
        b1, g1, beta1, m1, v1, b2, g2, beta2, m2, v2,
        (ushort4*)w1bf, (ushort4*)w2bf, sc1, bi1, sc2, bi2);

    sum_kernel<<<2048, 256, 0, stream>>>(t, sbf);

    zero_kernel<<<2048, 256, 0, stream>>>((float4*)d_out);

    gemm1_kernel<<<dim3(32, 64), 256, 0, stream>>>(sbf, w1bf, sc1, bi1, hbuf);

    gemm2_kernel<<<dim3(64, 8, 2), 256, 0, stream>>>(t, hbuf, w2bf, sc2, bi2, (float*)d_out);
}